// Round 2
// baseline (3499.939 us; speedup 1.0000x reference)
//
#include <hip/hip_runtime.h>
#include <cstdint>
#include <cmath>

// LLaMA block forward, B=1 S=2048 D=4096 H=32 HD=128 FF=11008, fp32 in/out,
// bf16 MFMA internal compute (harness threshold 0.127 is bf16-scale).
//
// Pipeline:
//   1. transpose-convert weights fp32 (K,N) -> bf16 (N,K); wg+w1 fused into one
//      contiguous (22016,4096) buffer so the FFN up-projection is ONE GEMM.
//   2. rmsnorm(x) -> xn bf16
//   3. q = xn@wq, k = xn@wk (128^2 gemm);  v GEMM stores transposed -> vt (D,S)
//   4. rope(q,k) in place
//   5. flash attention (causal-fold, dbuf LDS, 1 barrier/iter) -> attn bf16
//   6. attn@wo + x -> x2 fp32
//   7. rmsnorm(x2) -> xn2; gu = xn2@[wg|w1] (256^2 8-phase gemm);
//      h = silu(g)*u; h@w2 + x2 -> out (8-phase gemm, fp32+residual epilogue)
//
// gemm8 = plain-HIP port of the 256^2 8-phase schedule (T2+T3+T4+T5):
//   BK=64 split into two 32-wide k-half LDS slots [256 rows][32 cols] per mat,
//   double-buffered (8 slots, 128 KiB). Per phase: {ds_read one frag set |
//   stage ONE half-tile via global_load_lds | s_barrier | lgkmcnt(0) |
//   setprio(1) 16xMFMA setprio(0) | s_barrier}. vmcnt(6) only at phases 4/8
//   (counted, never 0 mid-loop). LDS bank-conflict fix: XOR-swizzle
//   p ^= ((p>>7)&3)<<4 applied to the pre-swizzled GLOBAL source address and
//   to the swizzled ds_read address; LDS stays linear for global_load_lds.

typedef unsigned short u16;
typedef unsigned int u32;
typedef __bf16 bf16x8 __attribute__((ext_vector_type(8)));
typedef float f32x4 __attribute__((ext_vector_type(4)));

__device__ __forceinline__ float bf2f(u16 u) {
    u32 x = ((u32)u) << 16; float f; __builtin_memcpy(&f, &x, 4); return f;
}
__device__ __forceinline__ u16 f2bf(float f) {
    u32 x; __builtin_memcpy(&x, &f, 4);
    u32 r = x + 0x7fff + ((x >> 16) & 1);   // RNE
    return (u16)(r >> 16);
}

// async global->LDS, 16B per lane (CK-style casts)
__device__ __forceinline__ void g2l16(const void* g, void* l) {
    auto* gp = reinterpret_cast<const u32*>(reinterpret_cast<uintptr_t>(g));
    auto* lp = reinterpret_cast<__attribute__((address_space(3))) u32*>(
        reinterpret_cast<uintptr_t>(l));
    __builtin_amdgcn_global_load_lds(gp, lp, 16, 0, 0);
}

#define FENCE asm volatile("" ::: "memory")
#define SBAR  do { FENCE; __builtin_amdgcn_s_barrier(); FENCE; } while (0)
#define WLGKM asm volatile("s_waitcnt lgkmcnt(0)" ::: "memory")
#define WVM6  asm volatile("s_waitcnt vmcnt(6)" ::: "memory")
#define WVM0  asm volatile("s_waitcnt vmcnt(0)" ::: "memory")

// ---------------------------------------------------------------------------
// Transpose + convert: in fp32 (K,N) row-major -> out bf16 (N,K) row-major.
__global__ __launch_bounds__(256) void transpose_f32_bf16(
    const float* __restrict__ in, u16* __restrict__ out, int K, int N) {
    __shared__ float tile[64][33];
    const int k0 = blockIdx.y * 64, n0 = blockIdx.x * 32;
    const int x = threadIdx.x, y = threadIdx.y;
#pragma unroll
    for (int i = 0; i < 8; i++) {
        int kr = y + i * 8;
        tile[kr][x] = in[(size_t)(k0 + kr) * N + n0 + x];
    }
    __syncthreads();
#pragma unroll
    for (int i = 0; i < 4; i++) {
        int nr = y + i * 8;
        u32 pk = (u32)f2bf(tile[2 * x][nr]) | ((u32)f2bf(tile[2 * x + 1][nr]) << 16);
        ((u32*)(out + (size_t)(n0 + nr) * K + k0))[x] = pk;
    }
}

// ---------------------------------------------------------------------------
// RMSNorm: fp32 in (row of 4096) -> bf16 out. One block per row.
__global__ __launch_bounds__(256) void rmsnorm_kernel(
    const float* __restrict__ x, const float* __restrict__ w, u16* __restrict__ o) {
    const int row = blockIdx.x;
    const float4* xr = (const float4*)(x + (size_t)row * 4096);
    float4 v[4];
    float ss = 0.f;
#pragma unroll
    for (int i = 0; i < 4; i++) {
        v[i] = xr[threadIdx.x + 256 * i];
        ss += v[i].x * v[i].x + v[i].y * v[i].y + v[i].z * v[i].z + v[i].w * v[i].w;
    }
#pragma unroll
    for (int off = 32; off > 0; off >>= 1) ss += __shfl_down(ss, off, 64);
    __shared__ float ws4[4];
    if ((threadIdx.x & 63) == 0) ws4[threadIdx.x >> 6] = ss;
    __syncthreads();
    float inv = rsqrtf((ws4[0] + ws4[1] + ws4[2] + ws4[3]) * (1.f / 4096.f) + 1e-5f);
    const float4* wr = (const float4*)w;
    u32* orow = (u32*)(o + (size_t)row * 4096);
#pragma unroll
    for (int i = 0; i < 4; i++) {
        float4 wv = wr[threadIdx.x + 256 * i];
        u32 lo = (u32)f2bf(v[i].x * inv * wv.x) | ((u32)f2bf(v[i].y * inv * wv.y) << 16);
        u32 hi = (u32)f2bf(v[i].z * inv * wv.z) | ((u32)f2bf(v[i].w * inv * wv.w) << 16);
        int idx = (threadIdx.x + 256 * i) * 2;
        orow[idx] = lo; orow[idx + 1] = hi;
    }
}

// ---------------------------------------------------------------------------
// RoPE in place on q (blockIdx.y=0) / k (blockIdx.y=1). One block per position.
__global__ __launch_bounds__(256) void rope_kernel(u16* __restrict__ q, u16* __restrict__ k) {
    const int s = blockIdx.x;
    u32* pr = (u32*)((blockIdx.y ? k : q) + (size_t)s * 4096);
#pragma unroll
    for (int it = 0; it < 8; it++) {
        int pidx = threadIdx.x + it * 256;      // pair index within row (0..2047)
        int i = pidx & 63;                      // freq index within head
        float ang = (float)s * expf(-(float)i * 0.14391156832817f); // 10000^(-2i/128)
        float sn, cs; sincosf(ang, &sn, &cs);
        u32 u = pr[pidx];
        float x1 = bf2f((u16)u), x2 = bf2f((u16)(u >> 16));
        pr[pidx] = (u32)f2bf(x1 * cs - x2 * sn) | ((u32)f2bf(x1 * sn + x2 * cs) << 16);
    }
}

// ---------------------------------------------------------------------------
// SiLU(g)*u elementwise from fused gu buffer (2048 x 22016 bf16):
// row r: cols [0,11008) = g, [11008,22016) = u. Output (2048 x 11008) bf16.
__global__ __launch_bounds__(256) void silu_mul_kernel(
    const u16* __restrict__ gu, u16* __restrict__ o) {
    u32 i = blockIdx.x * 256 + threadIdx.x;      // output uint4 idx, 2048*1376 total
    u32 row = i / 1376;
    u32 c = i - row * 1376;
    const uint4* grow = (const uint4*)gu + (size_t)row * 2752;
    uint4 gv = grow[c];
    uint4 uv = grow[c + 1376];
    const u32* gp = (const u32*)&gv;
    const u32* up = (const u32*)&uv;
    u32 rr[4];
#pragma unroll
    for (int j = 0; j < 4; j++) {
        float g0 = bf2f((u16)gp[j]), g1 = bf2f((u16)(gp[j] >> 16));
        float u0 = bf2f((u16)up[j]), u1 = bf2f((u16)(up[j] >> 16));
        float s0 = g0 / (1.f + __expf(-g0)) * u0;
        float s1 = g1 / (1.f + __expf(-g1)) * u1;
        rr[j] = (u32)f2bf(s0) | ((u32)f2bf(s1) << 16);
    }
    ((uint4*)o)[i] = *(const uint4*)rr;
}

// ---------------------------------------------------------------------------
// 128^2 GEMM (m97 structure) — kept for q/k/v/wo shapes.
// C(MxN) = A(MxK, row bf16) * B^T((N,K) row bf16).
template <int EPI>
__global__ __launch_bounds__(256) void gemm_bt(
    const u16* __restrict__ A, const u16* __restrict__ BT, void* __restrict__ Cout,
    const float* __restrict__ res, int M, int N, int K, int lda, int ldb, int ldc) {
    (void)M; (void)N;
    __shared__ u16 As[128 * 32];
    __shared__ u16 Bs[128 * 32];
    const int tid = threadIdx.x;
    const int lane = tid & 63, wave = tid >> 6;
    const int m0 = blockIdx.y * 128, n0 = blockIdx.x * 128;
    const int wm = (wave >> 1) * 64, wn = (wave & 1) * 64;
    const int gc = lane & 15, grp = lane >> 4;

    const u16* ga0 = A + (size_t)(m0 + (tid >> 2)) * lda + (tid & 3) * 8;
    const u16* ga1 = ga0 + (size_t)64 * lda;
    const u16* gb0 = BT + (size_t)(n0 + (tid >> 2)) * ldb + (tid & 3) * 8;
    const u16* gb1 = gb0 + (size_t)64 * ldb;
    u16* la0 = As + tid * 8;
    u16* la1 = As + tid * 8 + 2048;
    u16* lb0 = Bs + tid * 8;
    u16* lb1 = Bs + tid * 8 + 2048;

    f32x4 acc[4][4] = {};

    for (int k0 = 0; k0 < K; k0 += 32) {
        g2l16(ga0, la0); g2l16(ga1, la1);
        g2l16(gb0, lb0); g2l16(gb1, lb1);
        ga0 += 32; ga1 += 32; gb0 += 32; gb1 += 32;
        __syncthreads();
        bf16x8 af[4], bfr[4];
#pragma unroll
        for (int t = 0; t < 4; t++) {
            af[t]  = *(const bf16x8*)(As + (wm + t * 16 + gc) * 32 + grp * 8);
            bfr[t] = *(const bf16x8*)(Bs + (wn + t * 16 + gc) * 32 + grp * 8);
        }
#pragma unroll
        for (int mt = 0; mt < 4; mt++)
#pragma unroll
            for (int nt = 0; nt < 4; nt++)
                acc[mt][nt] = __builtin_amdgcn_mfma_f32_16x16x32_bf16(
                    af[mt], bfr[nt], acc[mt][nt], 0, 0, 0);
        __syncthreads();
    }

#pragma unroll
    for (int mt = 0; mt < 4; mt++) {
#pragma unroll
        for (int nt = 0; nt < 4; nt++) {
            int row0 = m0 + wm + mt * 16 + grp * 4;
            int col = n0 + wn + nt * 16 + gc;
            if (EPI == 0) {
                u16* C = (u16*)Cout;
#pragma unroll
                for (int r = 0; r < 4; r++)
                    C[(size_t)(row0 + r) * ldc + col] = f2bf(acc[mt][nt][r]);
            } else if (EPI == 1) {
                u16* C = (u16*)Cout;
                u32 p0 = (u32)f2bf(acc[mt][nt][0]) | ((u32)f2bf(acc[mt][nt][1]) << 16);
                u32 p1 = (u32)f2bf(acc[mt][nt][2]) | ((u32)f2bf(acc[mt][nt][3]) << 16);
                u32* dst = (u32*)(C + (size_t)col * ldc + row0);
                dst[0] = p0; dst[1] = p1;
            } else {
                float* C = (float*)Cout;
#pragma unroll
                for (int r = 0; r < 4; r++) {
                    size_t idx = (size_t)(row0 + r) * ldc + col;
                    C[idx] = acc[mt][nt][r] + res[idx];
                }
            }
        }
    }
}

// ---------------------------------------------------------------------------
// 256^2 8-phase GEMM. 512 threads = 8 waves (2M x 4N), per-wave 128x64 out.
// BK=64 as two 32-wide k-half slots per mat per buf: [256 rows][32 cols] bf16
// = 16KB each; 8 slots = 128KB dynamic LDS. Grid: 1-D, XCD-bijective swizzle
// (nblocks % 8 == 0 for all our shapes), cpx = nblocks/8; mt = swz/NT.
// EPI 0: bf16 C. EPI 2: fp32 C = acc + res.
__device__ __forceinline__ bf16x8 frd(const u16* lds, int slotu16, int lrow, int grp) {
    // logical p = lrow*64 + grp*16 bytes; swizzle p ^= ((p>>7)&3)<<4
    int idx = slotu16 + lrow * 32 + ((grp ^ ((lrow >> 1) & 3)) << 3);
    return *(const bf16x8*)(lds + idx);
}

template <int EPI>
__global__ __launch_bounds__(512, 2) void gemm8(
    const u16* __restrict__ A, const u16* __restrict__ BT, void* __restrict__ Cout,
    const float* __restrict__ res, int NT, int cpx, int K, int lda, int ldb, int ldc) {
    extern __shared__ u16 lds[];
    const int nkt = K >> 6;
    const int bid = blockIdx.x;
    const int swz = (bid & 7) * cpx + (bid >> 3);
    const int mt = swz / NT, nt = swz - mt * NT;
    const int m0 = mt << 8, n0 = nt << 8;
    const int tid = threadIdx.x, lane = tid & 63, wave = tid >> 6;
    const int wmi = wave >> 2, wni = wave & 3;
    const int gc = lane & 15, grp = lane >> 4;

    // stage source precompute: LDS-linear offset o -> logical (row, col)
    // o0 = tid*16 B, o1 = o0 + 8192 B ; p = o ^ (((o>>7)&3)<<4)
    const int o0 = tid * 16, o1 = o0 + 8192;
    const int p0 = o0 ^ (((o0 >> 7) & 3) << 4);
    const int p1 = o1 ^ (((o1 >> 7) & 3) << 4);
    const int r0 = p0 >> 6, c0 = (p0 & 63) >> 1;
    const int r1 = p1 >> 6, c1 = (p1 & 63) >> 1;
    const u16* gA0 = A + (size_t)(m0 + r0) * lda + c0;
    const u16* gA1 = A + (size_t)(m0 + r1) * lda + c1;
    const u16* gB0 = BT + (size_t)(n0 + r0) * ldb + c0;
    const u16* gB1 = BT + (size_t)(n0 + r1) * ldb + c1;
    u16* ld0 = lds + tid * 8;          // + slot u16 offset
    // slot u16 offsets: A: (buf*2+kh)*8192 ; B: 32768 + (buf*2+kh)*8192

    auto STA = [&](int buf, int kh, int ktS) {
        int slot = (buf * 2 + kh) * 8192;
        int ko = ktS * 64 + kh * 32;
        g2l16(gA0 + ko, ld0 + slot);
        g2l16(gA1 + ko, ld0 + slot + 4096);
    };
    auto STB = [&](int buf, int kh, int ktS) {
        int slot = 32768 + (buf * 2 + kh) * 8192;
        int ko = ktS * 64 + kh * 32;
        g2l16(gB0 + ko, ld0 + slot);
        g2l16(gB1 + ko, ld0 + slot + 4096);
    };

    f32x4 acc[8][4] = {};
    bf16x8 aA[8], aB[8], b[4];
    const int arow = wmi * 128 + gc;
    const int brow = wni * 64 + gc;

    auto RDA = [&](bf16x8* dst, int buf, int kh) {
        int slot = (buf * 2 + kh) * 8192;
#pragma unroll
        for (int m = 0; m < 8; m++) dst[m] = frd(lds, slot, arow + m * 16, grp);
    };
    auto RDB = [&](int buf, int kh) {
        int slot = 32768 + (buf * 2 + kh) * 8192;
#pragma unroll
        for (int n = 0; n < 4; n++) b[n] = frd(lds, slot, brow + n * 16, grp);
    };
    auto MM = [&](const bf16x8* af, int mlo) {
        __builtin_amdgcn_s_setprio(1);
#pragma unroll
        for (int m = 0; m < 4; m++)
#pragma unroll
            for (int n = 0; n < 4; n++)
                acc[mlo + m][n] = __builtin_amdgcn_mfma_f32_16x16x32_bf16(
                    af[mlo + m], b[n], acc[mlo + m][n], 0, 0, 0);
        __builtin_amdgcn_s_setprio(0);
    };

    // prologue: buf0 = kt0 (all 4 slots), buf1 = kt1 (A0,B0,A1; B1 staged at ph1)
    STA(0, 0, 0); STB(0, 0, 0); STA(0, 1, 0); STB(0, 1, 0);
    STA(1, 0, 1); STB(1, 0, 1); STA(1, 1, 1);
    WVM6;          // drain buf0's 8 loads (leaves buf1's 6 in flight)
    SBAR;

    for (int kt = 0; kt < nkt; kt += 2) {
        const bool pre = (kt + 2) < nkt;
        // ph1: read A(b0,k0); stage B(b1,k1)<-kt+1; deferred 2nd half of prev kh1(b1)
        RDA(aA, 0, 0);
        STB(1, 1, kt + 1);
        SBAR; WLGKM;
        if (kt) MM(aB, 4);
        SBAR;
        // ph2: read B(b0,k0); stage A(b0,k0)<-kt+2; kh0(b0) first half
        RDB(0, 0);
        if (pre) STA(0, 0, kt + 2);
        SBAR; WLGKM;
        MM(aA, 0);
        SBAR;
        // ph3: read A(b0,k1); stage B(b0,k0)<-kt+2; kh0(b0) second half
        RDA(aB, 0, 1);
        if (pre) STB(0, 0, kt + 2);
        SBAR; WLGKM;
        MM(aA, 4);
        SBAR;
        // ph4: read B(b0,k1); stage A(b0,k1)<-kt+2; kh1(b0) first half; vmcnt
        RDB(0, 1);
        if (pre) STA(0, 1, kt + 2);
        SBAR; WLGKM;
        MM(aB, 0);
        if (pre) { WVM6; } else { WVM0; }
        SBAR;
        // ph5: read A(b1,k0); stage B(b0,k1)<-kt+2; kh1(b0) second half
        RDA(aA, 1, 0);
        if (pre) STB(0, 1, kt + 2);
        SBAR; WLGKM;
        MM(aB, 4);
        SBAR;
        // ph6: read B(b1,k0); stage A(b1,k0)<-kt+3; kh0(b1) first half
        RDB(1, 0);
        if (pre) STA(1, 0, kt + 3);
        SBAR; WLGKM;
        MM(aA, 0);
        SBAR;
        // ph7: read A(b1,k1); stage B(b1,k0)<-kt+3; kh0(b1) second half
        RDA(aB, 1, 1);
        if (pre) STB(1, 0, kt + 3);
        SBAR; WLGKM;
        MM(aA, 4);
        SBAR;
        // ph8: read B(b1,k1); stage A(b1,k1)<-kt+3; kh1(b1) first half; vmcnt
        RDB(1, 1);
        if (pre) STA(1, 1, kt + 3);
        SBAR; WLGKM;
        MM(aB, 0);
        if (pre) { WVM6; } else { WVM0; }
        SBAR;
    }
    // deferred final: kh1(buf1) second half
    MM(aB, 4);

    // epilogue; C/D layout: col = lane&15, row = (lane>>4)*4 + reg
#pragma unroll
    for (int m = 0; m < 8; m++) {
#pragma unroll
        for (int n = 0; n < 4; n++) {
            int row0 = m0 + wmi * 128 + m * 16 + grp * 4;
            int col = n0 + wni * 64 + n * 16 + gc;
            if (EPI == 0) {
                u16* C = (u16*)Cout;
#pragma unroll
                for (int r = 0; r < 4; r++)
                    C[(size_t)(row0 + r) * ldc + col] = f2bf(acc[m][n][r]);
            } else {
                float* C = (float*)Cout;
#pragma unroll
                for (int r = 0; r < 4; r++) {
                    size_t idx = (size_t)(row0 + r) * ldc + col;
                    C[idx] = acc[m][n][r] + res[idx];
                }
            }
        }
    }
}

// ---------------------------------------------------------------------------
// Flash attention, causal-fold (see R0 notes). grid (8, H), 512 threads.
__global__ __launch_bounds__(512) void attn_kernel(
    const u16* __restrict__ q, const u16* __restrict__ k,
    const u16* __restrict__ vt, u16* __restrict__ o) {
    __shared__ u16 Ks[2][64][136];
    __shared__ u16 Vs[2][128][72];
    __shared__ u16 Ps[128][72];
    const int h = blockIdx.y;
    const int tid = threadIdx.x, lane = tid & 63, wave = tid >> 6;
    const int gc = lane & 15, grp = lane >> 4;
    const float scale = 0.08838834764831843f;

    const int ti0 = blockIdx.x;
    const int ti1 = 15 - (int)blockIdx.x;
    const int n0 = 2 * ti0 + 2;
    const int total = n0 + 2 * ti1 + 2;

    {
        uint4 kr0[2], vr0[2];
#pragma unroll
        for (int i = 0; i < 2; i++) {
            int c = tid + i * 512;
            kr0[i] = *(const uint4*)(k + (size_t)(c >> 4) * 4096 + h * 128 + (c & 15) * 8);
            vr0[i] = *(const uint4*)(vt + (size_t)(h * 128 + (c >> 3)) * 2048 + (c & 7) * 8);
        }
#pragma unroll
        for (int i = 0; i < 2; i++) {
            int c = tid + i * 512;
            *(uint4*)(&Ks[0][c >> 4][(c & 15) * 8]) = kr0[i];
            *(uint4*)(&Vs[0][c >> 3][(c & 7) * 8]) = vr0[i];
        }
    }
    __syncthreads();

    bf16x8 qf[4];
    f32x4 oacc[8];
    float mrun[4], lrun[4];
    const f32x4 fzero = {};
    int cur = 0;

    for (int it = 0; it < total; ++it) {
        const int t = (it >= n0) ? 1 : 0;
        const int local = t ? it - n0 : it;
        const int ti = t ? ti1 : ti0;
        const int j0 = local * 64;
        const int mw = ti * 128 + wave * 16;

        if (local == 0) {
#pragma unroll
            for (int ks = 0; ks < 4; ks++)
                qf[ks] = *(const bf16x8*)(q + (size_t)(mw + gc) * 4096 + h * 128 +
                                          ks * 32 + grp * 8);
#pragma unroll
            for (int nd = 0; nd < 8; nd++) oacc[nd] = fzero;
#pragma unroll
            for (int r = 0; r < 4; r++) { mrun[r] = -1e30f; lrun[r] = 0.f; }
        }

        const int itn = it + 1;
        const bool havenext = itn < total;
        const int jn = (itn >= n0 ? itn - n0 : itn) * 64;
        uint4 kreg[2], vreg[2];
        if (havenext) {
#pragma unroll
            for (int i = 0; i < 2; i++) {
                int c = tid + i * 512;
                kreg[i] = *(const uint4*)(k + (size_t)(jn + (c >> 4)) * 4096 +
                                          h * 128 + (c & 15) * 8);
                vreg[i] = *(const uint4*)(vt + (size_t)(h * 128 + (c >> 3)) * 2048 +
                                          jn + (c & 7) * 8);
            }
        }

        f32x4 sfr[4] = {};
#pragma unroll
        for (int ks = 0; ks < 4; ks++) {
            bf16x8 kf[4];
#pragma unroll
            for (int nt2 = 0; nt2 < 4; nt2++)
                kf[nt2] = *(const bf16x8*)(&Ks[cur][nt2 * 16 + gc][ks * 32 + grp * 8]);
#pragma unroll
            for (int nt2 = 0; nt2 < 4; nt2++)
                sfr[nt2] = __builtin_amdgcn_mfma_f32_16x16x32_bf16(
                    qf[ks], kf[nt2], sfr[nt2], 0, 0, 0);
        }

        if (j0 + 63 > mw) {
#pragma unroll
            for (int nt2 = 0; nt2 < 4; nt2++)
#pragma unroll
                for (int r = 0; r < 4; r++) {
                    int rowg = mw + grp * 4 + r;
                    int colg = j0 + nt2 * 16 + gc;
                    if (colg > rowg) sfr[nt2][r] = -3.0e38f;
                }
        }

#pragma unroll
        for (int r = 0; r < 4; r++) {
            float rm = fmaxf(fmaxf(sfr[0][r], sfr[1][r]),
                             fmaxf(sfr[2][r], sfr[3][r])) * scale;
#pragma unroll
            for (int msk = 1; msk < 16; msk <<= 1)
                rm = fmaxf(rm, __shfl_xor(rm, msk, 64));
            float mnew = fmaxf(mrun[r], rm);
            float alpha = __expf(mrun[r] - mnew);
            mrun[r] = mnew;
            float rs = 0.f;
#pragma unroll
            for (int nt2 = 0; nt2 < 4; nt2++) {
                float pv = __expf(sfr[nt2][r] * scale - mnew);
                sfr[nt2][r] = pv;
                rs += pv;
            }
#pragma unroll
            for (int msk = 1; msk < 16; msk <<= 1) rs += __shfl_xor(rs, msk, 64);
            lrun[r] = lrun[r] * alpha + rs;
#pragma unroll
            for (int nd = 0; nd < 8; nd++) oacc[nd][r] *= alpha;
        }

#pragma unroll
        for (int nt2 = 0; nt2 < 4; nt2++)
#pragma unroll
            for (int r = 0; r < 4; r++)
                Ps[wave * 16 + grp * 4 + r][nt2 * 16 + gc] = f2bf(sfr[nt2][r]);

#pragma unroll
        for (int ks2 = 0; ks2 < 2; ks2++) {
            bf16x8 pf = *(const bf16x8*)(&Ps[wave * 16 + gc][ks2 * 32 + grp * 8]);
#pragma unroll
            for (int nd = 0; nd < 8; nd++) {
                bf16x8 vf = *(const bf16x8*)(&Vs[cur][nd * 16 + gc][ks2 * 32 + grp * 8]);
                oacc[nd] = __builtin_amdgcn_mfma_f32_16x16x32_bf16(
                    pf, vf, oacc[nd], 0, 0, 0);
            }
        }

        if (havenext) {
#pragma unroll
            for (int i = 0; i < 2; i++) {
                int c = tid + i * 512;
                *(uint4*)(&Ks[cur ^ 1][c >> 4][(c & 15) * 8]) = kreg[i];
                *(uint4*)(&Vs[cur ^ 1][c >> 3][(c & 7) * 8]) = vreg[i];
            }
        }
        __syncthreads();
        cur ^= 1;

        if (local == 2 * ti + 1) {
#pragma unroll
            for (int r = 0; r < 4; r++) {
                float invl = 1.f / lrun[r];
                int rowg = mw + grp * 4 + r;
#pragma unroll
                for (int nd = 0; nd < 8; nd++)
                    o[(size_t)rowg * 4096 + h * 128 + nd * 16 + gc] =
                        f2bf(oacc[nd][r] * invl);
            }
        }
    }
}

// ---------------------------------------------------------------------------
extern "C" void kernel_launch(void* const* d_in, const int* in_sizes, int n_in,
                              void* d_out, int out_size, void* d_ws, size_t ws_size,
                              hipStream_t stream) {
    (void)in_sizes; (void)n_in; (void)out_size; (void)ws_size;
    const float* x    = (const float*)d_in[0];
    const float* ln_w = (const float*)d_in[1];
    const float* ffw  = (const float*)d_in[2];
    const float* wq   = (const float*)d_in[3];
    const float* wk   = (const float*)d_in[4];
    const float* wv   = (const float*)d_in[5];
    const float* wo   = (const float*)d_in[6];
    const float* wg   = (const float*)d_in[7];
    const float* w1   = (const float*)d_in[8];
    const float* w2   = (const float*)d_in[9];
    float* out = (float*)d_out;

    hipFuncSetAttribute(reinterpret_cast<const void*>(gemm8<0>),
                        hipFuncAttributeMaxDynamicSharedMemorySize, 131072);
    hipFuncSetAttribute(reinterpret_cast<const void*>(gemm8<2>),
                        hipFuncAttributeMaxDynamicSharedMemorySize, 131072);

    char* p = (char*)d_ws;
    auto alloc = [&](size_t n) { char* r = p; p += (n + 255) & ~(size_t)255; return r; };
    u16* wqT  = (u16*)alloc((size_t)4096 * 4096 * 2);
    u16* wkT  = (u16*)alloc((size_t)4096 * 4096 * 2);
    u16* wvT  = (u16*)alloc((size_t)4096 * 4096 * 2);
    u16* woT  = (u16*)alloc((size_t)4096 * 4096 * 2);
    u16* wguT = (u16*)alloc((size_t)22016 * 4096 * 2);   // [wg | w1] transposed
    u16* w2T  = (u16*)alloc((size_t)4096 * 11008 * 2);
    u16* xn   = (u16*)alloc((size_t)2048 * 4096 * 2);
    u16* qb   = (u16*)alloc((size_t)2048 * 4096 * 2);
    u16* kb   = (u16*)alloc((size_t)2048 * 4096 * 2);
    u16* vtb  = (u16*)alloc((size_t)4096 * 2048 * 2);
    u16* ab   = (u16*)alloc((size_t)2048 * 4096 * 2);
    float* x2 = (float*)alloc((size_t)2048 * 4096 * 4);
    u16* xn2  = (u16*)alloc((size_t)2048 * 4096 * 2);
    u16* gub  = (u16*)alloc((size_t)2048 * 22016 * 2);
    u16* gb   = (u16*)alloc((size_t)2048 * 11008 * 2);

    dim3 tb(32, 8);
    transpose_f32_bf16<<<dim3(128, 64), tb, 0, stream>>>(wq, wqT, 4096, 4096);
    transpose_f32_bf16<<<dim3(128, 64), tb, 0, stream>>>(wk, wkT, 4096, 4096);
    transpose_f32_bf16<<<dim3(128, 64), tb, 0, stream>>>(wv, wvT, 4096, 4096);
    transpose_f32_bf16<<<dim3(128, 64), tb, 0, stream>>>(wo, woT, 4096, 4096);
    transpose_f32_bf16<<<dim3(344, 64), tb, 0, stream>>>(wg, wguT, 4096, 11008);
    transpose_f32_bf16<<<dim3(344, 64), tb, 0, stream>>>(
        w1, wguT + (size_t)11008 * 4096, 4096, 11008);
    transpose_f32_bf16<<<dim3(128, 172), tb, 0, stream>>>(w2, w2T, 11008, 4096);

    rmsnorm_kernel<<<2048, 256, 0, stream>>>(x, ln_w, xn);

    gemm_bt<0><<<dim3(32, 16), 256, 0, stream>>>(xn, wqT, qb, nullptr,
                                                 2048, 4096, 4096, 4096, 4096, 4096);
    gemm_bt<0><<<dim3(32, 16), 256, 0, stream>>>(xn, wkT, kb, nullptr,
                                                 2048, 4096, 4096, 4096, 4096, 4096);
    gemm_bt<1><<<dim3(32, 16), 256, 0, stream>>>(xn, wvT, vtb, nullptr,
                                                 2048, 4096, 4096, 4096, 4096, 2048);

    rope_kernel<<<dim3(2048, 2), 256, 0, stream>>>(qb, kb);

    attn_kernel<<<dim3(8, 32), 512, 0, stream>>>(qb, kb, vtb, ab);

    gemm_bt<2><<<dim3(32, 16), 256, 0, stream>>>(ab, woT, x2, x,
                                                 2048, 4096, 4096, 4096, 4096, 4096);

    rmsnorm_kernel<<<2048, 256, 0, stream>>>(x2, ffw, xn2);

    // fused [g|u] = xn2 @ [wg|w1]: M=2048, N=22016, K=4096; 688 blocks (8x86)
    gemm8<0><<<688, 512, 131072, stream>>>(xn2, wguT, gub, nullptr,
                                           86, 86, 4096, 4096, 4096, 22016);

    silu_mul_kernel<<<11008, 256, 0, stream>>>(gub, gb);

    // out = h @ w2 + x2: M=2048, N=4096, K=11008; 128 blocks (8x16)
    gemm8<2><<<128, 512, 131072, stream>>>(gb, w2T, out, x2,
                                           16, 16, 11008, 11008, 11008, 4096);
}